// Round 10
// baseline (298.789 us; speedup 1.0000x reference)
//
#include <hip/hip_runtime.h>
#include <hip/hip_bf16.h>
#include <hip/hip_fp16.h>
#include <stdint.h>

#define B_ 128
#define C_ 64
#define F_ 129
#define D_ 512
#define K_ 8192
#define M_ (B_ * C_)  // 8192 tokens

typedef __attribute__((ext_vector_type(8))) _Float16 half8;
typedef __attribute__((ext_vector_type(4))) float f32x4;
typedef unsigned long long u64;

__device__ __forceinline__ ushort f2h(float f) {
  const _Float16 h = (_Float16)f;
  return __builtin_bit_cast(ushort, h);
}
__device__ __forceinline__ uint32_t fmap(float f) {
  uint32_t s = __float_as_uint(f);
  return s ^ ((s & 0x80000000u) ? 0xFFFFFFFFu : 0x80000000u);  // monotone
}
__device__ __forceinline__ float unfmap(uint32_t m) {
  return __uint_as_float((m & 0x80000000u) ? (m ^ 0x80000000u) : ~m);
}

// ---------------- Kernel A (fused): linear+z_f16  |  codebook f16 + e2 -----
// blocks [0,1024): z = x@W + b (8 tokens each; 1024 blocks = 4/CU for TLP)
// blocks [1024,3072): codebook -> f16 (4 rows each) + e2
__global__ __launch_bounds__(256) void k_prep(
    const float* __restrict__ x, const float* __restrict__ W,
    const float* __restrict__ bias, const float* __restrict__ cb,
    float* __restrict__ z, ushort* __restrict__ zf, ushort* __restrict__ cf,
    float* __restrict__ e2) {
  const int tid = threadIdx.x;
  if (blockIdx.x < 1024) {
    __shared__ float xs[8][F_];
    const int t0 = blockIdx.x * 8;
    const float* xsrc = x + (size_t)t0 * F_;
    for (int i = tid; i < 8 * F_; i += 256) xs[i / F_][i % F_] = xsrc[i];
    __syncthreads();
    float a0[8], a1[8];
#pragma unroll
    for (int r = 0; r < 8; ++r) { a0[r] = 0.f; a1[r] = 0.f; }
    const int c0 = tid, c1 = tid + 256;
    for (int f = 0; f < F_; ++f) {
      const float w0 = W[f * D_ + c0];
      const float w1 = W[f * D_ + c1];
#pragma unroll
      for (int r = 0; r < 8; ++r) {
        const float xv = xs[r][f];
        a0[r] = __builtin_fmaf(xv, w0, a0[r]);
        a1[r] = __builtin_fmaf(xv, w1, a1[r]);
      }
    }
    const float b0 = bias[c0], b1 = bias[c1];
#pragma unroll
    for (int r = 0; r < 8; ++r) {
      const size_t row = (size_t)(t0 + r) * D_;
      const float v0 = a0[r] + b0, v1 = a1[r] + b1;
      z[row + c0] = v0;
      z[row + c1] = v1;
      zf[row + c0] = f2h(v0);
      zf[row + c1] = f2h(v1);
    }
  } else {
    const int row = (blockIdx.x - 1024) * 4 + (tid >> 6);
    const int lane = tid & 63;
    const float* src = cb + (size_t)row * D_;
    float s = 0.f;
#pragma unroll
    for (int i = 0; i < 8; ++i) {
      const int d = lane + i * 64;
      const float v = src[d];
      s = __builtin_fmaf(v, v, s);
      cf[(size_t)row * D_ + d] = f2h(v);
    }
#pragma unroll
    for (int o = 32; o > 0; o >>= 1) s += __shfl_down(s, o);
    if (lane == 0) e2[row] = s;
  }
}

// ---------------- Kernel C: fused f16 GEMM + block top-2 -------------------
// Swapped operands: mfma(code_frag, token_frag) so C row=code, col=token
// (round-8: lane-local top-2, VALUBusy 60->34%). Structure = m97 ceiling.
__device__ __forceinline__ void stage_tile(const ushort* __restrict__ g,
                                           int r0, int k0, ushort* lds,
                                           int tid) {
  const int c = tid & 7;  // 16B column within the 128B row
#pragma unroll
  for (int i = 0; i < 4; ++i) {
    const int r = i * 32 + (tid >> 3);
    const int cs = c ^ (r & 7);  // inverse swizzle on the global source
    const ushort* src = g + (size_t)(r0 + r) * D_ + k0 + cs * 8;
    char* dst = (char*)lds + i * 4096 + (tid >> 6) * 1024;  // + lane*16 by HW
    __builtin_amdgcn_global_load_lds(
        (const __attribute__((address_space(1))) void*)src,
        (__attribute__((address_space(3))) void*)dst, 16, 0, 0);
  }
}

__global__ __launch_bounds__(256, 5) void k_argmin(
    const ushort* __restrict__ zf, const ushort* __restrict__ cf,
    const float* __restrict__ e2, u64* __restrict__ blk2) {
  __shared__ ushort lA[128 * 64], lB[128 * 64];
  const int tid = threadIdx.x;
  const int lane = tid & 63;
  const int w = tid >> 6;
  const int wr = (w >> 1) * 64;  // wave row offset in tile (tokens)
  const int wc = (w & 1) * 64;   // wave col offset in tile (codes)
  const int m0 = (blockIdx.x >> 6) * 128;  // token tile base
  const int n0 = (blockIdx.x & 63) * 128;  // code tile base

  f32x4 acc[4][4];  // [mc (code subtile)][nt (token subtile)]
#pragma unroll
  for (int m = 0; m < 4; ++m)
#pragma unroll
    for (int n = 0; n < 4; ++n) acc[m][n] = (f32x4){0.f, 0.f, 0.f, 0.f};

  for (int kt = 0; kt < D_ / 64; ++kt) {
    __syncthreads();  // previous compute done before overwriting LDS
    stage_tile(zf, m0, kt * 64, lA, tid);
    stage_tile(cf, n0, kt * 64, lB, tid);
    asm volatile("s_waitcnt vmcnt(0)" ::: "memory");
    __syncthreads();
#pragma unroll
    for (int ks = 0; ks < 2; ++ks) {
      half8 at[4], bc[4];
#pragma unroll
      for (int m = 0; m < 4; ++m) {
        const int row = wr + m * 16 + (lane & 15);
        const int cbo = (ks * 64 + ((lane >> 4) << 4)) ^ ((row & 7) << 4);
        at[m] = *(const half8*)((const char*)lA + row * 128 + cbo);
      }
#pragma unroll
      for (int n = 0; n < 4; ++n) {
        const int row = wc + n * 16 + (lane & 15);
        const int cbo = (ks * 64 + ((lane >> 4) << 4)) ^ ((row & 7) << 4);
        bc[n] = *(const half8*)((const char*)lB + row * 128 + cbo);
      }
#pragma unroll
      for (int mc = 0; mc < 4; ++mc)
#pragma unroll
        for (int nt = 0; nt < 4; ++nt)
          acc[mc][nt] = __builtin_amdgcn_mfma_f32_16x16x32_f16(
              bc[mc], at[nt], acc[mc][nt], 0, 0, 0);
    }
  }

  // Epilogue. acc[mc][nt][j]: code = n0+wc+mc*16+(lane>>4)*4+j (row),
  //                           token = m0+wr+nt*16+(lane&15)     (col).
  const int cbase = n0 + wc + ((lane >> 4) << 2);
  float e2r[4][4];
#pragma unroll
  for (int mc = 0; mc < 4; ++mc)
#pragma unroll
    for (int j = 0; j < 4; ++j) e2r[mc][j] = e2[cbase + mc * 16 + j];
  const int half = (n0 + wc) >> 6;  // global 64-code half index [0,128)
  const int tbase = m0 + wr;

#pragma unroll
  for (int nt = 0; nt < 4; ++nt) {
    float v1 = 3.0e38f, v2 = 3.0e38f;
    int i1 = 0, i2 = 0;
#pragma unroll
    for (int mc = 0; mc < 4; ++mc) {
#pragma unroll
      for (int j = 0; j < 4; ++j) {
        const float dd = __builtin_fmaf(-2.f, acc[mc][nt][j], e2r[mc][j]);
        const int ii = cbase + mc * 16 + j;
        const bool lt1 = dd < v1;
        const bool lt2 = dd < v2;
        v2 = lt1 ? v1 : (lt2 ? dd : v2);
        i2 = lt1 ? i1 : (lt2 ? ii : i2);
        v1 = lt1 ? dd : v1;
        i1 = lt1 ? ii : i1;
      }
    }
    // merge the 4 lane-groups (same token, different code ranges): o=16,32.
#pragma unroll
    for (int o = 16; o < 64; o <<= 1) {
      const float bv1 = __shfl_xor(v1, o), bv2 = __shfl_xor(v2, o);
      const int bi1 = __shfl_xor(i1, o), bi2 = __shfl_xor(i2, o);
      const bool t = bv1 < v1;
      const float hv = t ? v1 : bv1;
      const int hi = t ? i1 : bi1;
      v1 = t ? bv1 : v1;
      i1 = t ? bi1 : i1;
      const bool t2 = bv2 < v2;
      const float cv2 = t2 ? bv2 : v2;
      const int ci2 = t2 ? bi2 : i2;
      const bool t3 = hv < cv2;
      v2 = t3 ? hv : cv2;
      i2 = t3 ? hi : ci2;
    }
    if (lane < 16) {
      const int row = tbase + nt * 16 + lane;
      u64* dst = blk2 + (size_t)row * 256 + half * 2;  // token-major (r8)
      dst[0] = ((u64)fmap(v1) << 32) | (uint32_t)i1;
      dst[1] = ((u64)fmap(v2) << 32) | (uint32_t)i2;
    }
  }
}

// ---------------- Kernel D: top-4 + gap-gated exact rescore + output -------
// Fast path (gap > 0.5 >> 2*eps): all k != i0 have d_approx(k) >= v1 >
// v0 + 0.5, and |d_true - d_approx| <= ~0.1 -> true argmin = i0, skip the
// 4-row gather + f64 rescore (~96% of tokens). Wave-uniform branch.
#define CS(a, b)                          \
  {                                       \
    const u64 lo_ = (a < b) ? a : b;      \
    const u64 hi_ = (a < b) ? b : a;      \
    a = lo_;                              \
    b = hi_;                              \
  }

__global__ __launch_bounds__(256) void k_resolve(
    const u64* __restrict__ blk2, const float* __restrict__ cb,
    const float* __restrict__ z, const float* __restrict__ pos,
    float* __restrict__ out, float* __restrict__ lossp) {
  const int t = blockIdx.x * 4 + (threadIdx.x >> 6);
  const int lane = threadIdx.x & 63;
  const u64* kp = blk2 + (size_t)t * 256;
  u64 v0 = kp[lane * 4 + 0], v1 = kp[lane * 4 + 1];
  u64 v2 = kp[lane * 4 + 2], v3 = kp[lane * 4 + 3];
  // sort4
  CS(v0, v1) CS(v2, v3) CS(v0, v2) CS(v1, v3) CS(v1, v2)
  // butterfly merge: keep lowest-4 of (mine, theirs) at each level
#pragma unroll
  for (int o = 1; o < 64; o <<= 1) {
    const u64 b0 = __shfl_xor(v0, o), b1 = __shfl_xor(v1, o);
    const u64 b2 = __shfl_xor(v2, o), b3 = __shfl_xor(v3, o);
    u64 m0 = (v0 < b3) ? v0 : b3;
    u64 m1 = (v1 < b2) ? v1 : b2;
    u64 m2 = (v2 < b1) ? v2 : b1;
    u64 m3 = (v3 < b0) ? v3 : b0;
    CS(m0, m2) CS(m1, m3) CS(m0, m1) CS(m2, m3)
    v0 = m0; v1 = m1; v2 = m2; v3 = m3;
  }
  int sel = (int)(v0 & 0xFFFFFFFFull);
  const float ga = unfmap((uint32_t)(v1 >> 32)) - unfmap((uint32_t)(v0 >> 32));
  if (ga <= 0.5f) {  // slow path: exact f64 rescore of top-4
    const int i0 = (int)(v0 & 0xFFFFFFFFull);
    const int i1 = (int)(v1 & 0xFFFFFFFFull);
    const int i2 = (int)(v2 & 0xFFFFFFFFull);
    const int i3 = (int)(v3 & 0xFFFFFFFFull);
    const float* c0 = cb + (size_t)i0 * D_;
    const float* c1 = cb + (size_t)i1 * D_;
    const float* c2 = cb + (size_t)i2 * D_;
    const float* c3 = cb + (size_t)i3 * D_;
    const float* zr = z + (size_t)t * D_;
    double dt0 = 0.0, dt1 = 0.0, dt2 = 0.0, dt3 = 0.0;
    double q0 = 0.0, q1 = 0.0, q2 = 0.0, q3 = 0.0;
#pragma unroll
    for (int i = 0; i < 8; ++i) {
      const int d = lane + i * 64;
      const float zv = zr[d];
      const float a = c0[d], b = c1[d], c = c2[d], e = c3[d];
      dt0 += (double)zv * (double)a; q0 += (double)a * (double)a;
      dt1 += (double)zv * (double)b; q1 += (double)b * (double)b;
      dt2 += (double)zv * (double)c; q2 += (double)c * (double)c;
      dt3 += (double)zv * (double)e; q3 += (double)e * (double)e;
    }
#pragma unroll
    for (int o = 1; o < 64; o <<= 1) {
      dt0 += __shfl_xor(dt0, o); dt1 += __shfl_xor(dt1, o);
      dt2 += __shfl_xor(dt2, o); dt3 += __shfl_xor(dt3, o);
      q0 += __shfl_xor(q0, o); q1 += __shfl_xor(q1, o);
      q2 += __shfl_xor(q2, o); q3 += __shfl_xor(q3, o);
    }
    const double d0 = q0 - 2.0 * dt0;
    const double d1 = q1 - 2.0 * dt1;
    const double d2 = q2 - 2.0 * dt2;
    const double d3 = q3 - 2.0 * dt3;
    int bidx = i0;
    double bd = d0;
    if (d1 < bd || (d1 == bd && i1 < bidx)) { bd = d1; bidx = i1; }
    if (d2 < bd || (d2 == bd && i2 < bidx)) { bd = d2; bidx = i2; }
    if (d3 < bd || (d3 == bd && i3 < bidx)) { bd = d3; bidx = i3; }
    sel = bidx;
  }
  const float* q = cb + (size_t)sel * D_;
  const float* zr = z + (size_t)t * D_;
  const float* pe = pos + (size_t)(t & (C_ - 1)) * D_;
  float part = 0.f;
#pragma unroll
  for (int i = 0; i < 8; ++i) {
    const int d = lane + i * 64;
    const float qv = q[d];
    const float df = qv - zr[d];
    part = __builtin_fmaf(df, df, part);
    out[(size_t)t * D_ + d] = qv + pe[d];
  }
#pragma unroll
  for (int o = 32; o > 0; o >>= 1) part += __shfl_down(part, o);
  if (lane == 0) lossp[t] = part;
}

// ---------------- Kernel E: loss reduction ---------------------------------
__global__ __launch_bounds__(1024) void k_loss(const float* __restrict__ lossp,
                                               float* __restrict__ loss) {
  const int tid = threadIdx.x;
  float s = 0.f;
  for (int i = tid; i < M_; i += 1024) s += lossp[i];
#pragma unroll
  for (int o = 32; o > 0; o >>= 1) s += __shfl_down(s, o);
  __shared__ float red[16];
  if ((tid & 63) == 0) red[tid >> 6] = s;
  __syncthreads();
  if (tid == 0) {
    float tot = 0.f;
#pragma unroll
    for (int i = 0; i < 16; ++i) tot += red[i];
    *loss = tot * (1.0f / ((float)M_ * (float)D_));
  }
}

// ---------------- launch ---------------------------------------------------
extern "C" void kernel_launch(void* const* d_in, const int* in_sizes, int n_in,
                              void* d_out, int out_size, void* d_ws,
                              size_t ws_size, hipStream_t stream) {
  const float* x = (const float*)d_in[0];
  const float* W = (const float*)d_in[1];
  const float* bias = (const float*)d_in[2];
  const float* cb = (const float*)d_in[3];
  const float* pos = (const float*)d_in[4];
  float* out = (float*)d_out;
  float* loss = out + (size_t)M_ * D_;  // scalar commit_loss slot

  char* ws = (char*)d_ws;
  float* z = (float*)(ws + 0);                  // 16 MB
  ushort* zf = (ushort*)(ws + (16ull << 20));   // 8 MB
  ushort* cf = (ushort*)(ws + (24ull << 20));   // 8 MB
  float* e2 = (float*)(ws + (32ull << 20));     // 32 KB
  float* lossp = (float*)(ws + (32ull << 20) + 32768);  // 32 KB
  u64* blk2 = (u64*)(ws + (32ull << 20) + 65536);  // 16 MB [token][half][2]

  k_prep<<<1024 + K_ / 4, 256, 0, stream>>>(x, W, bias, cb, z, zf, cf, e2);
  k_argmin<<<(M_ / 128) * (K_ / 128), 256, 0, stream>>>(zf, cf, e2, blk2);
  k_resolve<<<M_ / 4, 256, 0, stream>>>(blk2, cb, z, pos, out, lossp);
  k_loss<<<1, 1024, 0, stream>>>(lossp, loss);
}

// Round 11
// 202.127 us; speedup vs baseline: 1.4782x; 1.4782x over previous
//
#include <hip/hip_runtime.h>
#include <hip/hip_bf16.h>
#include <hip/hip_fp16.h>
#include <stdint.h>

#define B_ 128
#define C_ 64
#define F_ 129
#define D_ 512
#define K_ 8192
#define M_ (B_ * C_)  // 8192 tokens

typedef __attribute__((ext_vector_type(8))) _Float16 half8;
typedef __attribute__((ext_vector_type(4))) float f32x4;
typedef unsigned long long u64;

__device__ __forceinline__ ushort f2h(float f) {
  const _Float16 h = (_Float16)f;
  return __builtin_bit_cast(ushort, h);
}
__device__ __forceinline__ uint32_t fmap(float f) {
  uint32_t s = __float_as_uint(f);
  return s ^ ((s & 0x80000000u) ? 0xFFFFFFFFu : 0x80000000u);  // monotone
}
__device__ __forceinline__ float unfmap(uint32_t m) {
  return __uint_as_float((m & 0x80000000u) ? (m ^ 0x80000000u) : ~m);
}

// ---------------- Kernel A (fused): linear+z_f16  |  codebook f16 + e2 -----
// blocks [0,1024): z = x@W + b (8 tokens each; TLP for the 129-deep chain)
// blocks [1024,3072): codebook -> f16 (4 rows each) + e2
__global__ __launch_bounds__(256) void k_prep(
    const float* __restrict__ x, const float* __restrict__ W,
    const float* __restrict__ bias, const float* __restrict__ cb,
    float* __restrict__ z, ushort* __restrict__ zf, ushort* __restrict__ cf,
    float* __restrict__ e2) {
  const int tid = threadIdx.x;
  if (blockIdx.x < 1024) {
    __shared__ float xs[8][F_];
    const int t0 = blockIdx.x * 8;
    const float* xsrc = x + (size_t)t0 * F_;
    for (int i = tid; i < 8 * F_; i += 256) xs[i / F_][i % F_] = xsrc[i];
    __syncthreads();
    float a0[8], a1[8];
#pragma unroll
    for (int r = 0; r < 8; ++r) { a0[r] = 0.f; a1[r] = 0.f; }
    const int c0 = tid, c1 = tid + 256;
    for (int f = 0; f < F_; ++f) {
      const float w0 = W[f * D_ + c0];
      const float w1 = W[f * D_ + c1];
#pragma unroll
      for (int r = 0; r < 8; ++r) {
        const float xv = xs[r][f];
        a0[r] = __builtin_fmaf(xv, w0, a0[r]);
        a1[r] = __builtin_fmaf(xv, w1, a1[r]);
      }
    }
    const float b0 = bias[c0], b1 = bias[c1];
#pragma unroll
    for (int r = 0; r < 8; ++r) {
      const size_t row = (size_t)(t0 + r) * D_;
      const float v0 = a0[r] + b0, v1 = a1[r] + b1;
      z[row + c0] = v0;
      z[row + c1] = v1;
      zf[row + c0] = f2h(v0);
      zf[row + c1] = f2h(v1);
    }
  } else {
    const int row = (blockIdx.x - 1024) * 4 + (tid >> 6);
    const int lane = tid & 63;
    const float* src = cb + (size_t)row * D_;
    float s = 0.f;
#pragma unroll
    for (int i = 0; i < 8; ++i) {
      const int d = lane + i * 64;
      const float v = src[d];
      s = __builtin_fmaf(v, v, s);
      cf[(size_t)row * D_ + d] = f2h(v);
    }
#pragma unroll
    for (int o = 32; o > 0; o >>= 1) s += __shfl_down(s, o);
    if (lane == 0) e2[row] = s;
  }
}

// ---------------- Kernel C: fused f16 GEMM + block top-2 -------------------
// Swapped operands: mfma(code_frag, token_frag) so C row=code, col=token.
// launch_bounds (256,4): measured VGPR 64, no spill (r8). (256,5) spilled
// the 64-VGPR accumulator to scratch -> 2.2x regression (r10 counters).
__device__ __forceinline__ void stage_tile(const ushort* __restrict__ g,
                                           int r0, int k0, ushort* lds,
                                           int tid) {
  const int c = tid & 7;  // 16B column within the 128B row
#pragma unroll
  for (int i = 0; i < 4; ++i) {
    const int r = i * 32 + (tid >> 3);
    const int cs = c ^ (r & 7);  // inverse swizzle on the global source
    const ushort* src = g + (size_t)(r0 + r) * D_ + k0 + cs * 8;
    char* dst = (char*)lds + i * 4096 + (tid >> 6) * 1024;  // + lane*16 by HW
    __builtin_amdgcn_global_load_lds(
        (const __attribute__((address_space(1))) void*)src,
        (__attribute__((address_space(3))) void*)dst, 16, 0, 0);
  }
}

__global__ __launch_bounds__(256, 4) void k_argmin(
    const ushort* __restrict__ zf, const ushort* __restrict__ cf,
    const float* __restrict__ e2, u64* __restrict__ blk2) {
  __shared__ ushort lA[128 * 64], lB[128 * 64];
  const int tid = threadIdx.x;
  const int lane = tid & 63;
  const int w = tid >> 6;
  const int wr = (w >> 1) * 64;  // wave row offset in tile (tokens)
  const int wc = (w & 1) * 64;   // wave col offset in tile (codes)
  const int m0 = (blockIdx.x >> 6) * 128;  // token tile base
  const int n0 = (blockIdx.x & 63) * 128;  // code tile base

  f32x4 acc[4][4];  // [mc (code subtile)][nt (token subtile)]
#pragma unroll
  for (int m = 0; m < 4; ++m)
#pragma unroll
    for (int n = 0; n < 4; ++n) acc[m][n] = (f32x4){0.f, 0.f, 0.f, 0.f};

  for (int kt = 0; kt < D_ / 64; ++kt) {
    __syncthreads();  // previous compute done before overwriting LDS
    stage_tile(zf, m0, kt * 64, lA, tid);
    stage_tile(cf, n0, kt * 64, lB, tid);
    asm volatile("s_waitcnt vmcnt(0)" ::: "memory");
    __syncthreads();
#pragma unroll
    for (int ks = 0; ks < 2; ++ks) {
      half8 at[4], bc[4];
#pragma unroll
      for (int m = 0; m < 4; ++m) {
        const int row = wr + m * 16 + (lane & 15);
        const int cbo = (ks * 64 + ((lane >> 4) << 4)) ^ ((row & 7) << 4);
        at[m] = *(const half8*)((const char*)lA + row * 128 + cbo);
      }
#pragma unroll
      for (int n = 0; n < 4; ++n) {
        const int row = wc + n * 16 + (lane & 15);
        const int cbo = (ks * 64 + ((lane >> 4) << 4)) ^ ((row & 7) << 4);
        bc[n] = *(const half8*)((const char*)lB + row * 128 + cbo);
      }
#pragma unroll
      for (int mc = 0; mc < 4; ++mc)
#pragma unroll
        for (int nt = 0; nt < 4; ++nt)
          acc[mc][nt] = __builtin_amdgcn_mfma_f32_16x16x32_f16(
              bc[mc], at[nt], acc[mc][nt], 0, 0, 0);
    }
  }

  // Epilogue. acc[mc][nt][j]: code = n0+wc+mc*16+(lane>>4)*4+j (row),
  //                           token = m0+wr+nt*16+(lane&15)     (col).
  const int cbase = n0 + wc + ((lane >> 4) << 2);
  float e2r[4][4];
#pragma unroll
  for (int mc = 0; mc < 4; ++mc)
#pragma unroll
    for (int j = 0; j < 4; ++j) e2r[mc][j] = e2[cbase + mc * 16 + j];
  const int half = (n0 + wc) >> 6;  // global 64-code half index [0,128)
  const int tbase = m0 + wr;

#pragma unroll
  for (int nt = 0; nt < 4; ++nt) {
    float v1 = 3.0e38f, v2 = 3.0e38f;
    int i1 = 0, i2 = 0;
#pragma unroll
    for (int mc = 0; mc < 4; ++mc) {
#pragma unroll
      for (int j = 0; j < 4; ++j) {
        const float dd = __builtin_fmaf(-2.f, acc[mc][nt][j], e2r[mc][j]);
        const int ii = cbase + mc * 16 + j;
        const bool lt1 = dd < v1;
        const bool lt2 = dd < v2;
        v2 = lt1 ? v1 : (lt2 ? dd : v2);
        i2 = lt1 ? i1 : (lt2 ? ii : i2);
        v1 = lt1 ? dd : v1;
        i1 = lt1 ? ii : i1;
      }
    }
    // merge the 4 lane-groups (same token, different code ranges): o=16,32.
#pragma unroll
    for (int o = 16; o < 64; o <<= 1) {
      const float bv1 = __shfl_xor(v1, o), bv2 = __shfl_xor(v2, o);
      const int bi1 = __shfl_xor(i1, o), bi2 = __shfl_xor(i2, o);
      const bool t = bv1 < v1;
      const float hv = t ? v1 : bv1;
      const int hi = t ? i1 : bi1;
      v1 = t ? bv1 : v1;
      i1 = t ? bi1 : i1;
      const bool t2 = bv2 < v2;
      const float cv2 = t2 ? bv2 : v2;
      const int ci2 = t2 ? bi2 : i2;
      const bool t3 = hv < cv2;
      v2 = t3 ? hv : cv2;
      i2 = t3 ? hi : ci2;
    }
    if (lane < 16) {
      const int row = tbase + nt * 16 + lane;
      u64* dst = blk2 + (size_t)row * 256 + half * 2;  // token-major (r8)
      dst[0] = ((u64)fmap(v1) << 32) | (uint32_t)i1;
      dst[1] = ((u64)fmap(v2) << 32) | (uint32_t)i2;
    }
  }
}

// ---------------- Kernel D: top-4 + gap-gated exact rescore + output -------
// Fast path (gap > 0.5 >> 2*eps): all k != i0 have d_approx(k) >= v1 >
// v0 + 0.5, and |d_true - d_approx| <= ~0.1 -> true argmin = i0, skip the
// 4-row gather + f64 rescore (~96% of tokens). Wave-uniform branch.
#define CS(a, b)                          \
  {                                       \
    const u64 lo_ = (a < b) ? a : b;      \
    const u64 hi_ = (a < b) ? b : a;      \
    a = lo_;                              \
    b = hi_;                              \
  }

__global__ __launch_bounds__(256) void k_resolve(
    const u64* __restrict__ blk2, const float* __restrict__ cb,
    const float* __restrict__ z, const float* __restrict__ pos,
    float* __restrict__ out, float* __restrict__ lossp) {
  const int t = blockIdx.x * 4 + (threadIdx.x >> 6);
  const int lane = threadIdx.x & 63;
  const u64* kp = blk2 + (size_t)t * 256;
  u64 v0 = kp[lane * 4 + 0], v1 = kp[lane * 4 + 1];
  u64 v2 = kp[lane * 4 + 2], v3 = kp[lane * 4 + 3];
  // sort4
  CS(v0, v1) CS(v2, v3) CS(v0, v2) CS(v1, v3) CS(v1, v2)
  // butterfly merge: keep lowest-4 of (mine, theirs) at each level
#pragma unroll
  for (int o = 1; o < 64; o <<= 1) {
    const u64 b0 = __shfl_xor(v0, o), b1 = __shfl_xor(v1, o);
    const u64 b2 = __shfl_xor(v2, o), b3 = __shfl_xor(v3, o);
    u64 m0 = (v0 < b3) ? v0 : b3;
    u64 m1 = (v1 < b2) ? v1 : b2;
    u64 m2 = (v2 < b1) ? v2 : b1;
    u64 m3 = (v3 < b0) ? v3 : b0;
    CS(m0, m2) CS(m1, m3) CS(m0, m1) CS(m2, m3)
    v0 = m0; v1 = m1; v2 = m2; v3 = m3;
  }
  int sel = (int)(v0 & 0xFFFFFFFFull);
  const float ga = unfmap((uint32_t)(v1 >> 32)) - unfmap((uint32_t)(v0 >> 32));
  if (ga <= 0.5f) {  // slow path: exact f64 rescore of top-4
    const int i0 = (int)(v0 & 0xFFFFFFFFull);
    const int i1 = (int)(v1 & 0xFFFFFFFFull);
    const int i2 = (int)(v2 & 0xFFFFFFFFull);
    const int i3 = (int)(v3 & 0xFFFFFFFFull);
    const float* c0 = cb + (size_t)i0 * D_;
    const float* c1 = cb + (size_t)i1 * D_;
    const float* c2 = cb + (size_t)i2 * D_;
    const float* c3 = cb + (size_t)i3 * D_;
    const float* zr = z + (size_t)t * D_;
    double dt0 = 0.0, dt1 = 0.0, dt2 = 0.0, dt3 = 0.0;
    double q0 = 0.0, q1 = 0.0, q2 = 0.0, q3 = 0.0;
#pragma unroll
    for (int i = 0; i < 8; ++i) {
      const int d = lane + i * 64;
      const float zv = zr[d];
      const float a = c0[d], b = c1[d], c = c2[d], e = c3[d];
      dt0 += (double)zv * (double)a; q0 += (double)a * (double)a;
      dt1 += (double)zv * (double)b; q1 += (double)b * (double)b;
      dt2 += (double)zv * (double)c; q2 += (double)c * (double)c;
      dt3 += (double)zv * (double)e; q3 += (double)e * (double)e;
    }
#pragma unroll
    for (int o = 1; o < 64; o <<= 1) {
      dt0 += __shfl_xor(dt0, o); dt1 += __shfl_xor(dt1, o);
      dt2 += __shfl_xor(dt2, o); dt3 += __shfl_xor(dt3, o);
      q0 += __shfl_xor(q0, o); q1 += __shfl_xor(q1, o);
      q2 += __shfl_xor(q2, o); q3 += __shfl_xor(q3, o);
    }
    const double d0 = q0 - 2.0 * dt0;
    const double d1 = q1 - 2.0 * dt1;
    const double d2 = q2 - 2.0 * dt2;
    const double d3 = q3 - 2.0 * dt3;
    int bidx = i0;
    double bd = d0;
    if (d1 < bd || (d1 == bd && i1 < bidx)) { bd = d1; bidx = i1; }
    if (d2 < bd || (d2 == bd && i2 < bidx)) { bd = d2; bidx = i2; }
    if (d3 < bd || (d3 == bd && i3 < bidx)) { bd = d3; bidx = i3; }
    sel = bidx;
  }
  const float* q = cb + (size_t)sel * D_;
  const float* zr = z + (size_t)t * D_;
  const float* pe = pos + (size_t)(t & (C_ - 1)) * D_;
  float part = 0.f;
#pragma unroll
  for (int i = 0; i < 8; ++i) {
    const int d = lane + i * 64;
    const float qv = q[d];
    const float df = qv - zr[d];
    part = __builtin_fmaf(df, df, part);
    out[(size_t)t * D_ + d] = qv + pe[d];
  }
#pragma unroll
  for (int o = 32; o > 0; o >>= 1) part += __shfl_down(part, o);
  if (lane == 0) lossp[t] = part;
}

// ---------------- Kernel E: loss reduction ---------------------------------
__global__ __launch_bounds__(1024) void k_loss(const float* __restrict__ lossp,
                                               float* __restrict__ loss) {
  const int tid = threadIdx.x;
  float s = 0.f;
  for (int i = tid; i < M_; i += 1024) s += lossp[i];
#pragma unroll
  for (int o = 32; o > 0; o >>= 1) s += __shfl_down(s, o);
  __shared__ float red[16];
  if ((tid & 63) == 0) red[tid >> 6] = s;
  __syncthreads();
  if (tid == 0) {
    float tot = 0.f;
#pragma unroll
    for (int i = 0; i < 16; ++i) tot += red[i];
    *loss = tot * (1.0f / ((float)M_ * (float)D_));
  }
}

// ---------------- launch ---------------------------------------------------
extern "C" void kernel_launch(void* const* d_in, const int* in_sizes, int n_in,
                              void* d_out, int out_size, void* d_ws,
                              size_t ws_size, hipStream_t stream) {
  const float* x = (const float*)d_in[0];
  const float* W = (const float*)d_in[1];
  const float* bias = (const float*)d_in[2];
  const float* cb = (const float*)d_in[3];
  const float* pos = (const float*)d_in[4];
  float* out = (float*)d_out;
  float* loss = out + (size_t)M_ * D_;  // scalar commit_loss slot

  char* ws = (char*)d_ws;
  float* z = (float*)(ws + 0);                  // 16 MB
  ushort* zf = (ushort*)(ws + (16ull << 20));   // 8 MB
  ushort* cf = (ushort*)(ws + (24ull << 20));   // 8 MB
  float* e2 = (float*)(ws + (32ull << 20));     // 32 KB
  float* lossp = (float*)(ws + (32ull << 20) + 32768);  // 32 KB
  u64* blk2 = (u64*)(ws + (32ull << 20) + 65536);  // 16 MB [token][half][2]

  k_prep<<<1024 + K_ / 4, 256, 0, stream>>>(x, W, bias, cb, z, zf, cf, e2);
  k_argmin<<<(M_ / 128) * (K_ / 128), 256, 0, stream>>>(zf, cf, e2, blk2);
  k_resolve<<<M_ / 4, 256, 0, stream>>>(blk2, cb, z, pos, out, lossp);
  k_loss<<<1, 1024, 0, stream>>>(lossp, loss);
}